// Round 6
// baseline (617.427 us; speedup 1.0000x reference)
//
#include <hip/hip_runtime.h>
#include <math.h>

#define B 128
#define N 512
#define H 512

typedef __attribute__((ext_vector_type(8))) short short8;
typedef __attribute__((ext_vector_type(4))) float floatx4;

typedef const __attribute__((address_space(1))) unsigned int* gas_t;
typedef __attribute__((address_space(3))) unsigned int* las_t;

__device__ __forceinline__ void gl16(const void* g, void* l){
    __builtin_amdgcn_global_load_lds((gas_t)g, (las_t)l, 16, 0, 0);
}

__device__ __forceinline__ float sigmoidf_(float x){ return 1.0f/(1.0f+__expf(-x)); }

// 7/7 pade tanh, clamped; err < 2e-4 everywhere, no exp (1/4-rate) needed
__device__ __forceinline__ float fast_tanh(float x){
    float xc = fminf(fmaxf(x, -4.97f), 4.97f);
    float x2 = xc*xc;
    float num = xc * (135135.0f + x2*(17325.0f + x2*(378.0f + x2)));
    float den = 135135.0f + x2*(62370.0f + x2*(3150.0f + x2*28.0f));
    return __fdividef(num, den);
}

// fp32 -> bf16 RNE
__device__ __forceinline__ unsigned f2bf1(float f){
    unsigned u = __float_as_uint(f);
    u += 0x7FFFu + ((u>>16)&1u);
    return u>>16;
}
__device__ __forceinline__ unsigned pk2(float a, float b){
    return f2bf1(a) | (f2bf1(b)<<16);
}

// ===== one fused cast kernel: weights (6656 rows) + small acts (128) + static A =====
__global__ __launch_bounds__(256) void k_cast_all(
    const float* __restrict__ encW, const float* __restrict__ tgtW,
    const float* __restrict__ ptrW, const float* __restrict__ wih,
    const float* __restrict__ whh,
    const float* __restrict__ dec, const float* __restrict__ lhh,
    const float* __restrict__ tgt, const float* __restrict__ sem,
    const float* __restrict__ A,
    unsigned short* __restrict__ We_s, unsigned short* __restrict__ Wt_s,
    unsigned short* __restrict__ Wp_s, unsigned short* __restrict__ We_d,
    unsigned short* __restrict__ Wt_d, unsigned short* __restrict__ Wp_c,
    unsigned short* __restrict__ Wp_e, unsigned short* __restrict__ Wih_b,
    unsigned short* __restrict__ Whh_b,
    unsigned short* __restrict__ Xbf, unsigned short* __restrict__ Hbf,
    unsigned short* __restrict__ Tbf, unsigned short* __restrict__ Sbf,
    unsigned short* __restrict__ Abf)
{
    int r = blockIdx.x, t = threadIdx.x;
    if (r < 6656){
        const float* src; unsigned short* dst; int pitch, off, row;
        if (r < 512)      { src=encW; dst=We_s; pitch=2*H; off=0;   row=r; }
        else if (r<1024)  { src=tgtW; dst=Wt_s; pitch=2*H; off=0;   row=r-512; }
        else if (r<1536)  { src=ptrW; dst=Wp_s; pitch=3*H; off=0;   row=r-1024; }
        else if (r<2048)  { src=encW; dst=We_d; pitch=2*H; off=H;   row=r-1536; }
        else if (r<2560)  { src=tgtW; dst=Wt_d; pitch=2*H; off=H;   row=r-2048; }
        else if (r<3072)  { src=ptrW; dst=Wp_c; pitch=3*H; off=H;   row=r-2560; }
        else if (r<3584)  { src=ptrW; dst=Wp_e; pitch=3*H; off=2*H; row=r-3072; }
        else if (r<5120)  { src=wih;  dst=Wih_b;pitch=H;   off=0;   row=r-3584; }
        else              { src=whh;  dst=Whh_b;pitch=H;   off=0;   row=r-5120; }
        float2 v = *(const float2*)&src[(size_t)row*pitch + off + 2*t];
        *(unsigned*)&dst[(size_t)row*H + 2*t] = pk2(v.x, v.y);
    } else if (r < 6784){
        int blk = r - 6656; int mat = blk >> 5;
        const float* src = mat==0?dec : mat==1?lhh : mat==2?tgt : sem;
        unsigned short* dst = mat==0?Xbf : mat==1?Hbf : mat==2?Tbf : Sbf;
        size_t i = ((size_t)(blk&31)*256 + t)*8;
        float4 lo = *(const float4*)&src[i];
        float4 hi = *(const float4*)&src[i+4];
        uint4 p;
        p.x = pk2(lo.x,lo.y); p.y = pk2(lo.z,lo.w);
        p.z = pk2(hi.x,hi.y); p.w = pk2(hi.z,hi.w);
        *(uint4*)&dst[i] = p;
    } else {
        size_t i = ((size_t)(r-6784)*256 + t)*8;
        float4 lo = *(const float4*)&A[i];
        float4 hi = *(const float4*)&A[i+4];
        uint4 p;
        p.x = pk2(lo.x,lo.y); p.y = pk2(lo.z,lo.w);
        p.z = pk2(hi.x,hi.y); p.w = pk2(hi.z,hi.w);
        *(uint4*)&Abf[i] = p;
    }
}

// ===== shared 128x128x512 bf16 MFMA tile (LDS version — used by small GEMMs) =====
__device__ __forceinline__ void gemm128_tile(
    const unsigned short* __restrict__ Ab,
    const unsigned short* __restrict__ Bb,
    float* __restrict__ C, int ldc)
{
    __shared__ __align__(16) unsigned short As[128*64];
    __shared__ __align__(16) unsigned short Bs[128*64];
    int t = threadIdx.x;
    int lane = t & 63, wave = t >> 6;
    int wy = wave >> 1, wx = wave & 1;
    int li = lane & 15, quad = lane >> 4;

    floatx4 acc[4][4];
    #pragma unroll
    for (int i=0;i<4;++i)
      #pragma unroll
      for (int j=0;j<4;++j) acc[i][j] = (floatx4)(0.0f);

    for (int kt=0; kt<8; ++kt){
        int k0 = kt*64;
        #pragma unroll
        for (int c=0;c<4;++c){
            int s = c*256 + t;
            int row = s >> 3;
            int kb = (s & 7) ^ (row & 7);
            gl16(&Ab[(size_t)row*512 + k0 + kb*8], &As[(size_t)s*8]);
            gl16(&Bb[(size_t)row*512 + k0 + kb*8], &Bs[(size_t)s*8]);
        }
        __syncthreads();
        #pragma unroll
        for (int ks=0;ks<2;++ks){
            short8 af[4], bg[4];
            #pragma unroll
            for (int i=0;i<4;++i){
                int m = wy*64 + i*16 + li;
                int kb = (ks*4 + quad) ^ (m&7);
                af[i] = *(const short8*)&As[m*64 + kb*8];
            }
            #pragma unroll
            for (int j=0;j<4;++j){
                int h = wx*64 + j*16 + li;
                int kb = (ks*4 + quad) ^ (h&7);
                bg[j] = *(const short8*)&Bs[h*64 + kb*8];
            }
            #pragma unroll
            for (int i=0;i<4;++i)
              #pragma unroll
              for (int j=0;j<4;++j)
                acc[i][j] = __builtin_amdgcn_mfma_f32_16x16x32_bf16(af[i], bg[j], acc[i][j], 0,0,0);
        }
        __syncthreads();
    }
    #pragma unroll
    for (int i=0;i<4;++i)
      #pragma unroll
      for (int j=0;j<4;++j)
        #pragma unroll
        for (int rg=0;rg<4;++rg){
            int m = wy*64 + i*16 + quad*4 + rg;
            int n = wx*64 + j*16 + li;
            C[(size_t)m*ldc + n] = acc[i][j][rg];
        }
}

// fp32-A variant (for dptr: ctx/ctxt are fp32)
__device__ __forceinline__ void gemm128_tile_f32A(
    const float* __restrict__ Af,
    const unsigned short* __restrict__ Bb,
    float* __restrict__ C, int ldc)
{
    __shared__ __align__(16) unsigned short As[128*64];
    __shared__ __align__(16) unsigned short Bs[128*64];
    int t = threadIdx.x;
    int lane = t & 63, wave = t >> 6;
    int wy = wave >> 1, wx = wave & 1;
    int li = lane & 15, quad = lane >> 4;

    floatx4 acc[4][4];
    #pragma unroll
    for (int i=0;i<4;++i)
      #pragma unroll
      for (int j=0;j<4;++j) acc[i][j] = (floatx4)(0.0f);

    for (int kt=0; kt<8; ++kt){
        int k0 = kt*64;
        #pragma unroll
        for (int c=0;c<4;++c){
            int s = c*256 + t;
            int row = s >> 3;
            int kb = (s & 7) ^ (row & 7);
            gl16(&Bb[(size_t)row*512 + k0 + kb*8], &Bs[(size_t)s*8]);
            const float* src = Af + (size_t)row*512 + k0 + kb*8;
            float4 lo = *(const float4*)src;
            float4 hi = *(const float4*)(src+4);
            uint4 p;
            p.x = pk2(lo.x,lo.y); p.y = pk2(lo.z,lo.w);
            p.z = pk2(hi.x,hi.y); p.w = pk2(hi.z,hi.w);
            *(uint4*)&As[(size_t)s*8] = p;
        }
        __syncthreads();
        #pragma unroll
        for (int ks=0;ks<2;++ks){
            short8 af[4], bg[4];
            #pragma unroll
            for (int i=0;i<4;++i){
                int m = wy*64 + i*16 + li;
                int kb = (ks*4 + quad) ^ (m&7);
                af[i] = *(const short8*)&As[m*64 + kb*8];
            }
            #pragma unroll
            for (int j=0;j<4;++j){
                int h = wx*64 + j*16 + li;
                int kb = (ks*4 + quad) ^ (h&7);
                bg[j] = *(const short8*)&Bs[h*64 + kb*8];
            }
            #pragma unroll
            for (int i=0;i<4;++i)
              #pragma unroll
              for (int j=0;j<4;++j)
                acc[i][j] = __builtin_amdgcn_mfma_f32_16x16x32_bf16(af[i], bg[j], acc[i][j], 0,0,0);
        }
        __syncthreads();
    }
    #pragma unroll
    for (int i=0;i<4;++i)
      #pragma unroll
      for (int j=0;j<4;++j)
        #pragma unroll
        for (int rg=0;rg<4;++rg){
            int m = wy*64 + i*16 + quad*4 + rg;
            int n = wx*64 + j*16 + li;
            C[(size_t)m*ldc + n] = acc[i][j][rg];
        }
}

// ---- merged pre-GEMMs (grid 32): gru gx/gh (24) + d_tgt (4) + d_se (4) ----
__global__ __launch_bounds__(256,2) void k_pre(
    const unsigned short* __restrict__ Xbf, const unsigned short* __restrict__ Hbf,
    const unsigned short* __restrict__ Tbf, const unsigned short* __restrict__ Sbf,
    const unsigned short* __restrict__ Wih_b, const unsigned short* __restrict__ Whh_b,
    const unsigned short* __restrict__ Wt_d, const unsigned short* __restrict__ Wp_e,
    float* __restrict__ gx, float* __restrict__ gh,
    float* __restrict__ d_tgt, float* __restrict__ d_se)
{
    int blk = blockIdx.x;
    if (blk < 24){
        int mat = blk / 12, nt = blk % 12;
        const unsigned short* Ab = mat ? Hbf : Xbf;
        const unsigned short* Bb = (mat ? Whh_b : Wih_b) + (size_t)nt*128*512;
        float* C = (mat ? gh : gx) + nt*128;
        gemm128_tile(Ab, Bb, C, 3*H);
    } else if (blk < 28){
        int nt = blk - 24;
        gemm128_tile(Tbf, Wt_d + (size_t)nt*128*512, d_tgt + nt*128, H);
    } else {
        int nt = blk - 28;
        gemm128_tile(Sbf, Wp_e + (size_t)nt*128*512, d_se + nt*128, H);
    }
}

// ---- GRU elementwise gates ----
__global__ __launch_bounds__(256) void k_gru_gate(const float* __restrict__ gx,
    const float* __restrict__ gh, const float* __restrict__ lhh,
    const float* __restrict__ bih, const float* __restrict__ bhh,
    float* __restrict__ out_hh, unsigned short* __restrict__ hnew_bf)
{
    int idx = blockIdx.x*256 + threadIdx.x;
    int b = idx >> 9, k = idx & 511;
    const float* gxb = gx + (size_t)b*(3*H);
    const float* ghb = gh + (size_t)b*(3*H);
    float r = sigmoidf_(gxb[k]     + bih[k]     + ghb[k]     + bhh[k]);
    float z = sigmoidf_(gxb[H+k]   + bih[H+k]   + ghb[H+k]   + bhh[H+k]);
    float n = tanhf(gxb[2*H+k] + bih[2*H+k] + r*(ghb[2*H+k] + bhh[2*H+k]));
    float h = (1.f-z)*n + z*lhh[idx];
    out_hh[idx] = h;
    hnew_bf[idx] = (unsigned short)f2bf1(h);
}

// ---- d_enc = hnew @ We_d^T (grid 4, after gate) ----
__global__ __launch_bounds__(256,2) void k_bias0(
    const unsigned short* __restrict__ HNbf, const unsigned short* __restrict__ We_d,
    float* __restrict__ d_enc)
{
    int nt = blockIdx.x;
    gemm128_tile(HNbf, We_d + (size_t)nt*128*512, d_enc + nt*128, H);
}

// ---- pointer biases GEMM (grid 8) ----
__global__ __launch_bounds__(256,2) void k_dptr_gemm(
    const float* __restrict__ ctx, const float* __restrict__ ctxt,
    const unsigned short* __restrict__ Wp_c,
    float* __restrict__ d_pe, float* __restrict__ d_pt)
{
    int blk = blockIdx.x;
    int mat = blk >> 2, nt = blk & 3;
    const float* Af = mat ? ctxt : ctx;
    const unsigned short* Bb = Wp_c + (size_t)nt*128*512;
    float* C = (mat ? d_pt : d_pe) + nt*128;
    gemm128_tile_f32A(Af, Bb, C, H);
}

// ---- frag loader: bf16 direct (1x b128) or fp32 direct (2x b128 + pack) ----
template<bool BF16>
__device__ __forceinline__ short8 load_frag(const unsigned short* pb, const float* pf, int off){
    if constexpr (BF16){
        return *(const short8*)(pb + off);
    } else {
        float4 lo = *(const float4*)(pf + off);
        float4 hi = *(const float4*)(pf + off + 4);
        uint4 p;
        p.x = pk2(lo.x,lo.y); p.y = pk2(lo.z,lo.w);
        p.z = pk2(hi.x,hi.y); p.w = pk2(hi.z,hi.w);
        union { uint4 u; short8 s; } cv; cv.u = p;
        return cv.s;
    }
}

// ---- fused enc+tgt MFMA scores (grid 2048): NO LDS, frags direct from global ----
template<bool BF16A>
__global__ __launch_bounds__(256,2) void k_scores_fused(
    const float* __restrict__ Af, const unsigned short* __restrict__ Abf,
    const unsigned short* __restrict__ We, const unsigned short* __restrict__ Wt,
    const float* __restrict__ d_enc, const float* __restrict__ d_tgt,
    const float* __restrict__ enc_v, const float* __restrict__ tgt_v,
    float* __restrict__ sc_e, float* __restrict__ sc_t)
{
    int blk = blockIdx.x;
    int b = blk >> 4; int nt = (blk >> 2) & 3; int ht = blk & 3;
    int n0 = nt*128, hb = ht*128;
    int t = threadIdx.x;
    int lane = t & 63, wave = t >> 6;
    int wy = wave >> 1, wx = wave & 1;
    int li = lane & 15, quad = lane >> 4;

    // per-lane base pointers (frag layout: A[m=li][k=quad*8+j], B[n=li][k=quad*8+j])
    const unsigned short* pA[4]; const float* pAf[4];
    #pragma unroll
    for (int i=0;i<4;++i){
        size_t r = (size_t)(b*N + n0 + wy*64 + i*16 + li)*H + quad*8;
        if constexpr (BF16A) pA[i] = Abf + r; else pAf[i] = Af + r;
    }
    const unsigned short* pE[4]; const unsigned short* pT[4];
    #pragma unroll
    for (int j=0;j<4;++j){
        size_t r = (size_t)(hb + wx*64 + j*16 + li)*H + quad*8;
        pE[j] = We + r; pT[j] = Wt + r;
    }

    floatx4 acc_e[4][4], acc_t[4][4];
    #pragma unroll
    for (int i=0;i<4;++i)
      #pragma unroll
      for (int j=0;j<4;++j){ acc_e[i][j]=(floatx4)(0.0f); acc_t[i][j]=(floatx4)(0.0f); }

    #pragma unroll
    for (int kk=0; kk<16; ++kk){     // K-step = 32; offsets are immediates
        int off = kk*32;
        short8 af[4], be[4], bt[4];
        #pragma unroll
        for (int i=0;i<4;++i) af[i] = load_frag<BF16A>(pA[i], pAf[i], off);
        #pragma unroll
        for (int j=0;j<4;++j){
            be[j] = *(const short8*)(pE[j] + off);
            bt[j] = *(const short8*)(pT[j] + off);
        }
        #pragma unroll
        for (int i=0;i<4;++i)
          #pragma unroll
          for (int j=0;j<4;++j){
            acc_e[i][j] = __builtin_amdgcn_mfma_f32_16x16x32_bf16(af[i], be[j], acc_e[i][j], 0,0,0);
            acc_t[i][j] = __builtin_amdgcn_mfma_f32_16x16x32_bf16(af[i], bt[j], acc_t[i][j], 0,0,0);
          }
    }

    float nse[4][4], nst[4][4];
    #pragma unroll
    for (int i=0;i<4;++i)
      #pragma unroll
      for (int rg=0;rg<4;++rg){ nse[i][rg]=0.f; nst[i][rg]=0.f; }
    #pragma unroll
    for (int j=0;j<4;++j){
        int hm = hb + wx*64 + j*16 + li;
        float dje = d_enc[b*H+hm], vje = enc_v[hm];
        float djt = d_tgt[b*H+hm], vjt = tgt_v[hm];
        #pragma unroll
        for (int i=0;i<4;++i)
          #pragma unroll
          for (int rg=0;rg<4;++rg){
            nse[i][rg] += vje * fast_tanh(acc_e[i][j][rg] + dje);
            nst[i][rg] += vjt * fast_tanh(acc_t[i][j][rg] + djt);
          }
    }
    #pragma unroll
    for (int off=1; off<16; off<<=1)
      #pragma unroll
      for (int i=0;i<4;++i)
        #pragma unroll
        for (int rg=0;rg<4;++rg){
          nse[i][rg] += __shfl_xor(nse[i][rg], off);
          nst[i][rg] += __shfl_xor(nst[i][rg], off);
        }
    if (li==0){
        #pragma unroll
        for (int i=0;i<4;++i)
          #pragma unroll
          for (int rg=0;rg<4;++rg){
            atomicAdd(&sc_e[b*N + n0 + wy*64 + i*16 + quad*4 + rg], nse[i][rg]);
            atomicAdd(&sc_t[b*N + n0 + wy*64 + i*16 + quad*4 + rg], nst[i][rg]);
          }
    }
}

// ---------------- softmax both score rows ----------------
__global__ __launch_bounds__(256) void k_softmax(const float* __restrict__ sc_e,
    const float* __restrict__ sc_t, float* __restrict__ w_e, float* __restrict__ w_t)
{
    __shared__ float buf[256];
    int b = blockIdx.x, t = threadIdx.x;
    float x0 = sc_e[b*N+t], x1 = sc_e[b*N+t+256];
    float m = fmaxf(x0,x1);
    buf[t]=m; __syncthreads();
    for (int s2=128;s2>0;s2>>=1){ if(t<s2) buf[t]=fmaxf(buf[t],buf[t+s2]); __syncthreads(); }
    m = buf[0]; __syncthreads();
    float e0 = __expf(x0-m), e1 = __expf(x1-m);
    buf[t]=e0+e1; __syncthreads();
    for (int s2=128;s2>0;s2>>=1){ if(t<s2) buf[t]+=buf[t+s2]; __syncthreads(); }
    float inv = 1.0f/buf[0]; __syncthreads();
    w_e[b*N+t]=e0*inv; w_e[b*N+t+256]=e1*inv;
    x0 = sc_t[b*N+t]; x1 = sc_t[b*N+t+256];
    m = fmaxf(x0,x1);
    buf[t]=m; __syncthreads();
    for (int s2=128;s2>0;s2>>=1){ if(t<s2) buf[t]=fmaxf(buf[t],buf[t+s2]); __syncthreads(); }
    m = buf[0]; __syncthreads();
    e0 = __expf(x0-m); e1 = __expf(x1-m);
    buf[t]=e0+e1; __syncthreads();
    for (int s2=128;s2>0;s2>>=1){ if(t<s2) buf[t]+=buf[t+s2]; __syncthreads(); }
    inv = 1.0f/buf[0];
    w_t[b*N+t]=e0*inv; w_t[b*N+t+256]=e1*inv;
}

// ---------------- context from bf16 A ----------------
__global__ __launch_bounds__(256) void k_context_bf16(const unsigned short* __restrict__ Abf,
    const float* __restrict__ w_e, const float* __restrict__ w_t,
    float* __restrict__ ctx, float* __restrict__ ctxt)
{
    __shared__ float we[64], wt[64];
    int b = blockIdx.x >> 3, c = blockIdx.x & 7, t = threadIdx.x;
    int n0 = c*64;
    if (t < 64){ we[t]=w_e[b*N+n0+t]; wt[t]=w_t[b*N+n0+t]; }
    __syncthreads();
    float ae0=0.f, ae1=0.f, at0=0.f, at1=0.f;
    for (int n=0;n<64;++n){
        unsigned u = *(const unsigned*)&Abf[(size_t)(b*N+n0+n)*H + 2*t];
        float lo = __uint_as_float(u<<16);
        float hi = __uint_as_float(u & 0xFFFF0000u);
        float e = we[n], g = wt[n];
        ae0 += e*lo; ae1 += e*hi; at0 += g*lo; at1 += g*hi;
    }
    atomicAdd(&ctx[b*H+2*t],   ae0); atomicAdd(&ctx[b*H+2*t+1],  ae1);
    atomicAdd(&ctxt[b*H+2*t],  at0); atomicAdd(&ctxt[b*H+2*t+1], at1);
}

// ---------------- context from fp32 A (fallback) ----------------
__global__ __launch_bounds__(256) void k_context(const float* __restrict__ A,
    const float* __restrict__ w_e, const float* __restrict__ w_t,
    float* __restrict__ ctx, float* __restrict__ ctxt)
{
    __shared__ float we[128], wt[128];
    int b = blockIdx.x >> 2, c = blockIdx.x & 3, t = threadIdx.x;
    int n0 = c*128;
    if (t < 128){ we[t]=w_e[b*N+n0+t]; wt[t]=w_t[b*N+n0+t]; }
    __syncthreads();
    float ae0=0.f, ae1=0.f, at0=0.f, at1=0.f;
    for (int n=0;n<128;++n){
        const float* ar = A + (size_t)(b*N + n0 + n)*H;
        float a0 = ar[t], a1 = ar[t+256];
        ae0 += we[n]*a0; ae1 += we[n]*a1;
        at0 += wt[n]*a0; at1 += wt[n]*a1;
    }
    atomicAdd(&ctx[b*H+t],      ae0); atomicAdd(&ctx[b*H+t+256],  ae1);
    atomicAdd(&ctxt[b*H+t],     at0); atomicAdd(&ctxt[b*H+t+256], at1);
}

// ---- MFMA pointer scores (grid 2048): NO LDS, direct frags; two tanh epilogues ----
template<bool BF16A>
__global__ __launch_bounds__(256,2) void k_probs_mfma(
    const float* __restrict__ Af, const unsigned short* __restrict__ Abf,
    const unsigned short* __restrict__ Wp,
    const float* __restrict__ d_pe, const float* __restrict__ d_pt,
    const float* __restrict__ d_se,
    const float* __restrict__ ptr_v, float* __restrict__ probs)
{
    int blk = blockIdx.x;
    int b = blk >> 4; int nt = (blk >> 2) & 3; int ht = blk & 3;
    int n0 = nt*128, hb = ht*128;
    int t = threadIdx.x;
    int lane = t & 63, wave = t >> 6;
    int wy = wave >> 1, wx = wave & 1;
    int li = lane & 15, quad = lane >> 4;

    const unsigned short* pA[4]; const float* pAf[4];
    #pragma unroll
    for (int i=0;i<4;++i){
        size_t r = (size_t)(b*N + n0 + wy*64 + i*16 + li)*H + quad*8;
        if constexpr (BF16A) pA[i] = Abf + r; else pAf[i] = Af + r;
    }
    const unsigned short* pB[4];
    #pragma unroll
    for (int j=0;j<4;++j)
        pB[j] = Wp + (size_t)(hb + wx*64 + j*16 + li)*H + quad*8;

    floatx4 acc[4][4];
    #pragma unroll
    for (int i=0;i<4;++i)
      #pragma unroll
      for (int j=0;j<4;++j) acc[i][j] = (floatx4)(0.0f);

    #pragma unroll
    for (int kk=0; kk<16; ++kk){
        int off = kk*32;
        short8 af[4], bg[4];
        #pragma unroll
        for (int i=0;i<4;++i) af[i] = load_frag<BF16A>(pA[i], pAf[i], off);
        #pragma unroll
        for (int j=0;j<4;++j) bg[j] = *(const short8*)(pB[j] + off);
        #pragma unroll
        for (int i=0;i<4;++i)
          #pragma unroll
          for (int j=0;j<4;++j)
            acc[i][j] = __builtin_amdgcn_mfma_f32_16x16x32_bf16(af[i], bg[j], acc[i][j], 0,0,0);
    }

    float nsum[4][4];
    #pragma unroll
    for (int i=0;i<4;++i){ nsum[i][0]=0.f;nsum[i][1]=0.f;nsum[i][2]=0.f;nsum[i][3]=0.f; }
    #pragma unroll
    for (int j=0;j<4;++j){
        int hm = hb + wx*64 + j*16 + li;
        float se = d_se[b*H + hm];
        float de = d_pe[b*H + hm] + se;
        float dt = d_pt[b*H + hm] + se;
        float vj = ptr_v[hm];
        #pragma unroll
        for (int i=0;i<4;++i)
          #pragma unroll
          for (int rg=0;rg<4;++rg){
            float s = acc[i][j][rg];
            nsum[i][rg] += vj * (5.0f*fast_tanh(s + de) + fast_tanh(s + dt));
          }
    }
    #pragma unroll
    for (int off=1; off<16; off<<=1)
      #pragma unroll
      for (int i=0;i<4;++i)
        #pragma unroll
        for (int rg=0;rg<4;++rg)
          nsum[i][rg] += __shfl_xor(nsum[i][rg], off);
    if (li==0){
        #pragma unroll
        for (int i=0;i<4;++i)
          #pragma unroll
          for (int rg=0;rg<4;++rg)
            atomicAdd(&probs[b*N + n0 + wy*64 + i*16 + quad*4 + rg], nsum[i][rg]);
    }
}

extern "C" void kernel_launch(void* const* d_in, const int* in_sizes, int n_in,
                              void* d_out, int out_size, void* d_ws, size_t ws_size,
                              hipStream_t stream)
{
    (void)in_sizes; (void)n_in; (void)out_size;
    const float* A    = (const float*)d_in[0];
    const float* sem  = (const float*)d_in[1];
    const float* dec  = (const float*)d_in[2];
    const float* tgt  = (const float*)d_in[3];
    const float* lhh  = (const float*)d_in[4];
    const float* ptrv = (const float*)d_in[5];
    const float* ptrW = (const float*)d_in[6];
    const float* encv = (const float*)d_in[7];
    const float* encW = (const float*)d_in[8];
    const float* tgtv = (const float*)d_in[9];
    const float* tgtW = (const float*)d_in[10];
    const float* wih  = (const float*)d_in[11];
    const float* whh  = (const float*)d_in[12];
    const float* bih  = (const float*)d_in[13];
    const float* bhh  = (const float*)d_in[14];

    float* probs_out = (float*)d_out;
    float* hh_out    = (float*)d_out + B*N;

    float* ws = (float*)d_ws;
    const size_t S = (size_t)B*H;          // 65536
    float* d_enc = ws;
    float* d_tgt = ws + S;
    float* d_se  = ws + 2*S;
    float* sc_e  = ws + 3*S;
    float* sc_t  = ws + 4*S;
    float* ctx   = ws + 5*S;
    float* ctxt  = ws + 6*S;
    float* w_e   = ws + 7*S;
    float* w_t   = ws + 8*S;
    float* d_pe  = ws + 9*S;
    float* d_pt  = ws + 10*S;
    float* gx    = ws + 11*S;              // 3S
    float* gh    = ws + 14*S;              // 3S
    unsigned short* bfb  = (unsigned short*)(ws + 17*S);
    const size_t WH = (size_t)H*H;
    const size_t WG = (size_t)3*H*H;
    unsigned short* We_s  = bfb;
    unsigned short* Wt_s  = We_s + WH;
    unsigned short* Wp_s  = Wt_s + WH;
    unsigned short* We_d  = Wp_s + WH;
    unsigned short* Wt_d  = We_d + WH;
    unsigned short* Wp_c  = Wt_d + WH;
    unsigned short* Wp_e  = Wp_c + WH;
    unsigned short* Wih_b = Wp_e + WH;
    unsigned short* Whh_b = Wih_b + WG;
    unsigned short* Xbf   = Whh_b + WG;
    unsigned short* Hbf   = Xbf + S;
    unsigned short* Tbf   = Hbf + S;
    unsigned short* Sbf   = Tbf + S;
    unsigned short* HNbf  = Sbf + S;
    unsigned short* Abf   = HNbf + S;

    const size_t need_full = 17*S*sizeof(float)
        + (7*WH + 2*WG + 5*S + (size_t)B*N*H) * sizeof(unsigned short);
    const bool big = ws_size >= need_full;

    hipMemsetAsync(sc_e, 0, 4*S*sizeof(float), stream);   // sc_e, sc_t, ctx, ctxt
    hipMemsetAsync(probs_out, 0, (size_t)B*N*sizeof(float), stream);

    int castA_blocks = big ? (int)(((size_t)B*N*H)/(256*8)) : 0;
    k_cast_all<<<6784 + castA_blocks, 256, 0, stream>>>(encW, tgtW, ptrW, wih, whh,
        dec, lhh, tgt, sem, A,
        We_s, Wt_s, Wp_s, We_d, Wt_d, Wp_c, Wp_e, Wih_b, Whh_b,
        Xbf, Hbf, Tbf, Sbf, Abf);

    k_pre<<<32, 256, 0, stream>>>(Xbf, Hbf, Tbf, Sbf, Wih_b, Whh_b, Wt_d, Wp_e,
        gx, gh, d_tgt, d_se);
    k_gru_gate<<<256, 256, 0, stream>>>(gx, gh, lhh, bih, bhh, hh_out, HNbf);
    k_bias0<<<4, 256, 0, stream>>>(HNbf, We_d, d_enc);

    if (big)
        k_scores_fused<true ><<<2048, 256, 0, stream>>>(A, Abf, We_s, Wt_s, d_enc, d_tgt, encv, tgtv, sc_e, sc_t);
    else
        k_scores_fused<false><<<2048, 256, 0, stream>>>(A, Abf, We_s, Wt_s, d_enc, d_tgt, encv, tgtv, sc_e, sc_t);
    k_softmax<<<B, 256, 0, stream>>>(sc_e, sc_t, w_e, w_t);
    if (big)
        k_context_bf16<<<B*8, 256, 0, stream>>>(Abf, w_e, w_t, ctx, ctxt);
    else
        k_context<<<B*4, 256, 0, stream>>>(A, w_e, w_t, ctx, ctxt);

    k_dptr_gemm<<<8, 256, 0, stream>>>(ctx, ctxt, Wp_c, d_pe, d_pt);

    if (big)
        k_probs_mfma<true ><<<2048, 256, 0, stream>>>(A, Abf, Wp_s, d_pe, d_pt, d_se, ptrv, probs_out);
    else
        k_probs_mfma<false><<<2048, 256, 0, stream>>>(A, Abf, Wp_s, d_pe, d_pt, d_se, ptrv, probs_out);
}

// Round 7
// 473.629 us; speedup vs baseline: 1.3036x; 1.3036x over previous
//
#include <hip/hip_runtime.h>
#include <math.h>

#define B 128
#define N 512
#define H 512

typedef __attribute__((ext_vector_type(8))) short short8;
typedef __attribute__((ext_vector_type(4))) float floatx4;

typedef const __attribute__((address_space(1))) unsigned int* gas_t;
typedef __attribute__((address_space(3))) unsigned int* las_t;

__device__ __forceinline__ void gl16(const void* g, void* l){
    __builtin_amdgcn_global_load_lds((gas_t)g, (las_t)l, 16, 0, 0);
}

__device__ __forceinline__ float sigmoidf_(float x){ return 1.0f/(1.0f+__expf(-x)); }

// 7/7 pade tanh, clamped; err < 2e-4, no exp needed
__device__ __forceinline__ float fast_tanh(float x){
    float xc = fminf(fmaxf(x, -4.97f), 4.97f);
    float x2 = xc*xc;
    float num = xc * (135135.0f + x2*(17325.0f + x2*(378.0f + x2)));
    float den = 135135.0f + x2*(62370.0f + x2*(3150.0f + x2*28.0f));
    return __fdividef(num, den);
}

// fp32 -> bf16 RNE
__device__ __forceinline__ unsigned f2bf1(float f){
    unsigned u = __float_as_uint(f);
    u += 0x7FFFu + ((u>>16)&1u);
    return u>>16;
}
__device__ __forceinline__ unsigned pk2(float a, float b){
    return f2bf1(a) | (f2bf1(b)<<16);
}

// ===== one fused cast kernel: weights (6656 rows) + small acts (128) + static A =====
__global__ __launch_bounds__(256) void k_cast_all(
    const float* __restrict__ encW, const float* __restrict__ tgtW,
    const float* __restrict__ ptrW, const float* __restrict__ wih,
    const float* __restrict__ whh,
    const float* __restrict__ dec, const float* __restrict__ lhh,
    const float* __restrict__ tgt, const float* __restrict__ sem,
    const float* __restrict__ A,
    unsigned short* __restrict__ We_s, unsigned short* __restrict__ Wt_s,
    unsigned short* __restrict__ Wp_s, unsigned short* __restrict__ We_d,
    unsigned short* __restrict__ Wt_d, unsigned short* __restrict__ Wp_c,
    unsigned short* __restrict__ Wp_e, unsigned short* __restrict__ Wih_b,
    unsigned short* __restrict__ Whh_b,
    unsigned short* __restrict__ Xbf, unsigned short* __restrict__ Hbf,
    unsigned short* __restrict__ Tbf, unsigned short* __restrict__ Sbf,
    unsigned short* __restrict__ Abf)
{
    int r = blockIdx.x, t = threadIdx.x;
    if (r < 6656){
        const float* src; unsigned short* dst; int pitch, off, row;
        if (r < 512)      { src=encW; dst=We_s; pitch=2*H; off=0;   row=r; }
        else if (r<1024)  { src=tgtW; dst=Wt_s; pitch=2*H; off=0;   row=r-512; }
        else if (r<1536)  { src=ptrW; dst=Wp_s; pitch=3*H; off=0;   row=r-1024; }
        else if (r<2048)  { src=encW; dst=We_d; pitch=2*H; off=H;   row=r-1536; }
        else if (r<2560)  { src=tgtW; dst=Wt_d; pitch=2*H; off=H;   row=r-2048; }
        else if (r<3072)  { src=ptrW; dst=Wp_c; pitch=3*H; off=H;   row=r-2560; }
        else if (r<3584)  { src=ptrW; dst=Wp_e; pitch=3*H; off=2*H; row=r-3072; }
        else if (r<5120)  { src=wih;  dst=Wih_b;pitch=H;   off=0;   row=r-3584; }
        else              { src=whh;  dst=Whh_b;pitch=H;   off=0;   row=r-5120; }
        float2 v = *(const float2*)&src[(size_t)row*pitch + off + 2*t];
        *(unsigned*)&dst[(size_t)row*H + 2*t] = pk2(v.x, v.y);
    } else if (r < 6784){
        int blk = r - 6656; int mat = blk >> 5;
        const float* src = mat==0?dec : mat==1?lhh : mat==2?tgt : sem;
        unsigned short* dst = mat==0?Xbf : mat==1?Hbf : mat==2?Tbf : Sbf;
        size_t i = ((size_t)(blk&31)*256 + t)*8;
        float4 lo = *(const float4*)&src[i];
        float4 hi = *(const float4*)&src[i+4];
        uint4 p;
        p.x = pk2(lo.x,lo.y); p.y = pk2(lo.z,lo.w);
        p.z = pk2(hi.x,hi.y); p.w = pk2(hi.z,hi.w);
        *(uint4*)&dst[i] = p;
    } else {
        size_t i = ((size_t)(r-6784)*256 + t)*8;
        float4 lo = *(const float4*)&A[i];
        float4 hi = *(const float4*)&A[i+4];
        uint4 p;
        p.x = pk2(lo.x,lo.y); p.y = pk2(lo.z,lo.w);
        p.z = pk2(hi.x,hi.y); p.w = pk2(hi.z,hi.w);
        *(uint4*)&Abf[i] = p;
    }
}

// ===== shared 128x128x512 bf16 MFMA tile (LDS, for small GEMMs) =====
__device__ __forceinline__ void gemm128_tile(
    const unsigned short* __restrict__ Ab,
    const unsigned short* __restrict__ Bb,
    float* __restrict__ C, int ldc)
{
    __shared__ __align__(16) unsigned short As[128*64];
    __shared__ __align__(16) unsigned short Bs[128*64];
    int t = threadIdx.x;
    int lane = t & 63, wave = t >> 6;
    int wy = wave >> 1, wx = wave & 1;
    int li = lane & 15, quad = lane >> 4;

    floatx4 acc[4][4];
    #pragma unroll
    for (int i=0;i<4;++i)
      #pragma unroll
      for (int j=0;j<4;++j) acc[i][j] = (floatx4)(0.0f);

    for (int kt=0; kt<8; ++kt){
        int k0 = kt*64;
        #pragma unroll
        for (int c=0;c<4;++c){
            int s = c*256 + t;
            int row = s >> 3;
            int kb = (s & 7) ^ (row & 7);
            gl16(&Ab[(size_t)row*512 + k0 + kb*8], &As[(size_t)s*8]);
            gl16(&Bb[(size_t)row*512 + k0 + kb*8], &Bs[(size_t)s*8]);
        }
        __syncthreads();
        #pragma unroll
        for (int ks=0;ks<2;++ks){
            short8 af[4], bg[4];
            #pragma unroll
            for (int i=0;i<4;++i){
                int m = wy*64 + i*16 + li;
                int kb = (ks*4 + quad) ^ (m&7);
                af[i] = *(const short8*)&As[m*64 + kb*8];
            }
            #pragma unroll
            for (int j=0;j<4;++j){
                int h = wx*64 + j*16 + li;
                int kb = (ks*4 + quad) ^ (h&7);
                bg[j] = *(const short8*)&Bs[h*64 + kb*8];
            }
            #pragma unroll
            for (int i=0;i<4;++i)
              #pragma unroll
              for (int j=0;j<4;++j)
                acc[i][j] = __builtin_amdgcn_mfma_f32_16x16x32_bf16(af[i], bg[j], acc[i][j], 0,0,0);
        }
        __syncthreads();
    }
    #pragma unroll
    for (int i=0;i<4;++i)
      #pragma unroll
      for (int j=0;j<4;++j)
        #pragma unroll
        for (int rg=0;rg<4;++rg){
            int m = wy*64 + i*16 + quad*4 + rg;
            int n = wx*64 + j*16 + li;
            C[(size_t)m*ldc + n] = acc[i][j][rg];
        }
}

// fp32-A variant (for dptr)
__device__ __forceinline__ void gemm128_tile_f32A(
    const float* __restrict__ Af,
    const unsigned short* __restrict__ Bb,
    float* __restrict__ C, int ldc)
{
    __shared__ __align__(16) unsigned short As[128*64];
    __shared__ __align__(16) unsigned short Bs[128*64];
    int t = threadIdx.x;
    int lane = t & 63, wave = t >> 6;
    int wy = wave >> 1, wx = wave & 1;
    int li = lane & 15, quad = lane >> 4;

    floatx4 acc[4][4];
    #pragma unroll
    for (int i=0;i<4;++i)
      #pragma unroll
      for (int j=0;j<4;++j) acc[i][j] = (floatx4)(0.0f);

    for (int kt=0; kt<8; ++kt){
        int k0 = kt*64;
        #pragma unroll
        for (int c=0;c<4;++c){
            int s = c*256 + t;
            int row = s >> 3;
            int kb = (s & 7) ^ (row & 7);
            gl16(&Bb[(size_t)row*512 + k0 + kb*8], &Bs[(size_t)s*8]);
            const float* src = Af + (size_t)row*512 + k0 + kb*8;
            float4 lo = *(const float4*)src;
            float4 hi = *(const float4*)(src+4);
            uint4 p;
            p.x = pk2(lo.x,lo.y); p.y = pk2(lo.z,lo.w);
            p.z = pk2(hi.x,hi.y); p.w = pk2(hi.z,hi.w);
            *(uint4*)&As[(size_t)s*8] = p;
        }
        __syncthreads();
        #pragma unroll
        for (int ks=0;ks<2;++ks){
            short8 af[4], bg[4];
            #pragma unroll
            for (int i=0;i<4;++i){
                int m = wy*64 + i*16 + li;
                int kb = (ks*4 + quad) ^ (m&7);
                af[i] = *(const short8*)&As[m*64 + kb*8];
            }
            #pragma unroll
            for (int j=0;j<4;++j){
                int h = wx*64 + j*16 + li;
                int kb = (ks*4 + quad) ^ (h&7);
                bg[j] = *(const short8*)&Bs[h*64 + kb*8];
            }
            #pragma unroll
            for (int i=0;i<4;++i)
              #pragma unroll
              for (int j=0;j<4;++j)
                acc[i][j] = __builtin_amdgcn_mfma_f32_16x16x32_bf16(af[i], bg[j], acc[i][j], 0,0,0);
        }
        __syncthreads();
    }
    #pragma unroll
    for (int i=0;i<4;++i)
      #pragma unroll
      for (int j=0;j<4;++j)
        #pragma unroll
        for (int rg=0;rg<4;++rg){
            int m = wy*64 + i*16 + quad*4 + rg;
            int n = wx*64 + j*16 + li;
            C[(size_t)m*ldc + n] = acc[i][j][rg];
        }
}

// ---- merged pre-GEMMs (grid 32): gru gx/gh (24) + d_tgt (4) + d_se (4) ----
__global__ __launch_bounds__(256,2) void k_pre(
    const unsigned short* __restrict__ Xbf, const unsigned short* __restrict__ Hbf,
    const unsigned short* __restrict__ Tbf, const unsigned short* __restrict__ Sbf,
    const unsigned short* __restrict__ Wih_b, const unsigned short* __restrict__ Whh_b,
    const unsigned short* __restrict__ Wt_d, const unsigned short* __restrict__ Wp_e,
    float* __restrict__ gx, float* __restrict__ gh,
    float* __restrict__ d_tgt, float* __restrict__ d_se)
{
    int blk = blockIdx.x;
    if (blk < 24){
        int mat = blk / 12, nt = blk % 12;
        const unsigned short* Ab = mat ? Hbf : Xbf;
        const unsigned short* Bb = (mat ? Whh_b : Wih_b) + (size_t)nt*128*512;
        float* C = (mat ? gh : gx) + nt*128;
        gemm128_tile(Ab, Bb, C, 3*H);
    } else if (blk < 28){
        int nt = blk - 24;
        gemm128_tile(Tbf, Wt_d + (size_t)nt*128*512, d_tgt + nt*128, H);
    } else {
        int nt = blk - 28;
        gemm128_tile(Sbf, Wp_e + (size_t)nt*128*512, d_se + nt*128, H);
    }
}

// ---- GRU elementwise gates ----
__global__ __launch_bounds__(256) void k_gru_gate(const float* __restrict__ gx,
    const float* __restrict__ gh, const float* __restrict__ lhh,
    const float* __restrict__ bih, const float* __restrict__ bhh,
    float* __restrict__ out_hh, unsigned short* __restrict__ hnew_bf)
{
    int idx = blockIdx.x*256 + threadIdx.x;
    int b = idx >> 9, k = idx & 511;
    const float* gxb = gx + (size_t)b*(3*H);
    const float* ghb = gh + (size_t)b*(3*H);
    float r = sigmoidf_(gxb[k]     + bih[k]     + ghb[k]     + bhh[k]);
    float z = sigmoidf_(gxb[H+k]   + bih[H+k]   + ghb[H+k]   + bhh[H+k]);
    float n = tanhf(gxb[2*H+k] + bih[2*H+k] + r*(ghb[2*H+k] + bhh[2*H+k]));
    float h = (1.f-z)*n + z*lhh[idx];
    out_hh[idx] = h;
    hnew_bf[idx] = (unsigned short)f2bf1(h);
}

// ---- d_enc = hnew @ We_d^T (grid 4) ----
__global__ __launch_bounds__(256,2) void k_bias0(
    const unsigned short* __restrict__ HNbf, const unsigned short* __restrict__ We_d,
    float* __restrict__ d_enc)
{
    int nt = blockIdx.x;
    gemm128_tile(HNbf, We_d + (size_t)nt*128*512, d_enc + nt*128, H);
}

// ---- pointer biases GEMM (grid 8) ----
__global__ __launch_bounds__(256,2) void k_dptr_gemm(
    const float* __restrict__ ctx, const float* __restrict__ ctxt,
    const unsigned short* __restrict__ Wp_c,
    float* __restrict__ d_pe, float* __restrict__ d_pt)
{
    int blk = blockIdx.x;
    int mat = blk >> 2, nt = blk & 3;
    const float* Af = mat ? ctxt : ctx;
    const unsigned short* Bb = Wp_c + (size_t)nt*128*512;
    float* C = (mat ? d_pt : d_pe) + nt*128;
    gemm128_tile_f32A(Af, Bb, C, H);
}

// ---- fused enc+tgt MFMA scores (grid 2048): LDS staging, hoisted pointers ----
template<bool BF16A>
__global__ __launch_bounds__(256,2) void k_scores_fused(
    const float* __restrict__ Af, const unsigned short* __restrict__ Abf,
    const unsigned short* __restrict__ We, const unsigned short* __restrict__ Wt,
    const float* __restrict__ d_enc, const float* __restrict__ d_tgt,
    const float* __restrict__ enc_v, const float* __restrict__ tgt_v,
    float* __restrict__ sc_e, float* __restrict__ sc_t)
{
    __shared__ __align__(16) unsigned short As[128*64];
    __shared__ __align__(16) unsigned short Be[128*64];
    __shared__ __align__(16) unsigned short Bt[128*64];
    int blk = blockIdx.x;
    int b = blk >> 4; int nt = (blk >> 2) & 3; int ht = blk & 3;
    int n0 = nt*128, hb = ht*128;
    int t = threadIdx.x;
    int lane = t & 63, wave = t >> 6;
    int wy = wave >> 1, wx = wave & 1;
    int li = lane & 15, quad = lane >> 4;

    floatx4 acc_e[4][4], acc_t[4][4];
    #pragma unroll
    for (int i=0;i<4;++i)
      #pragma unroll
      for (int j=0;j<4;++j){ acc_e[i][j]=(floatx4)(0.0f); acc_t[i][j]=(floatx4)(0.0f); }

    // frag LDS base pointers: address = (base_row+imm_row)*64 + kb*8, kb=(ks*4+quad)^(li&7)
    const unsigned short* rA[2]; const unsigned short* rE[2]; const unsigned short* rT[2];
    #pragma unroll
    for (int ks=0;ks<2;++ks){
        int kb = (ks*4 + quad) ^ (li & 7);
        rA[ks] = &As[(wy*64 + li)*64 + kb*8];
        rE[ks] = &Be[(wx*64 + li)*64 + kb*8];
        rT[ks] = &Bt[(wx*64 + li)*64 + kb*8];
    }

    if constexpr (BF16A){
        // staging pointers (c,kt-invariant swizzle)
        int rs = t >> 3;                      // 0..31
        int kb = (t & 7) ^ (rs & 7);
        const unsigned short* gA[4]; const unsigned short* gE[4]; const unsigned short* gT[4];
        unsigned short* lA[4]; unsigned short* lE[4]; unsigned short* lT[4];
        #pragma unroll
        for (int c=0;c<4;++c){
            int row = c*32 + rs;
            gA[c] = Abf + (size_t)(b*N + n0 + row)*H + kb*8;
            gE[c] = We  + (size_t)(hb + row)*H + kb*8;
            gT[c] = Wt  + (size_t)(hb + row)*H + kb*8;
            int s = c*256 + t;
            lA[c] = &As[(size_t)s*8]; lE[c] = &Be[(size_t)s*8]; lT[c] = &Bt[(size_t)s*8];
        }
        for (int kt=0; kt<8; ++kt){
            #pragma unroll
            for (int c=0;c<4;++c){
                gl16(gA[c], lA[c]); gA[c] += 64;
                gl16(gE[c], lE[c]); gE[c] += 64;
                gl16(gT[c], lT[c]); gT[c] += 64;
            }
            __syncthreads();
            #pragma unroll
            for (int ks=0;ks<2;++ks){
                short8 af[4], be[4], bt[4];
                #pragma unroll
                for (int i=0;i<4;++i) af[i] = *(const short8*)(rA[ks] + i*1024);
                #pragma unroll
                for (int j=0;j<4;++j){
                    be[j] = *(const short8*)(rE[ks] + j*1024);
                    bt[j] = *(const short8*)(rT[ks] + j*1024);
                }
                #pragma unroll
                for (int i=0;i<4;++i)
                  #pragma unroll
                  for (int j=0;j<4;++j){
                    acc_e[i][j] = __builtin_amdgcn_mfma_f32_16x16x32_bf16(af[i], be[j], acc_e[i][j], 0,0,0);
                    acc_t[i][j] = __builtin_amdgcn_mfma_f32_16x16x32_bf16(af[i], bt[j], acc_t[i][j], 0,0,0);
                  }
            }
            __syncthreads();
        }
    } else {
        for (int kt=0; kt<8; ++kt){
            int k0 = kt*64;
            #pragma unroll
            for (int c=0;c<4;++c){
                int s = c*256 + t;
                int row = s >> 3;
                int kb = (s & 7) ^ (row & 7);
                const float* src = Af + (size_t)(b*N+n0+row)*H + k0 + kb*8;
                float4 lo = *(const float4*)src;
                float4 hi = *(const float4*)(src+4);
                uint4 p;
                p.x = pk2(lo.x,lo.y); p.y = pk2(lo.z,lo.w);
                p.z = pk2(hi.x,hi.y); p.w = pk2(hi.z,hi.w);
                *(uint4*)&As[(size_t)s*8] = p;
                gl16(&We[(size_t)(hb+row)*H + k0 + kb*8], &Be[(size_t)s*8]);
                gl16(&Wt[(size_t)(hb+row)*H + k0 + kb*8], &Bt[(size_t)s*8]);
            }
            __syncthreads();
            #pragma unroll
            for (int ks=0;ks<2;++ks){
                short8 af[4], be[4], bt[4];
                #pragma unroll
                for (int i=0;i<4;++i) af[i] = *(const short8*)(rA[ks] + i*1024);
                #pragma unroll
                for (int j=0;j<4;++j){
                    be[j] = *(const short8*)(rE[ks] + j*1024);
                    bt[j] = *(const short8*)(rT[ks] + j*1024);
                }
                #pragma unroll
                for (int i=0;i<4;++i)
                  #pragma unroll
                  for (int j=0;j<4;++j){
                    acc_e[i][j] = __builtin_amdgcn_mfma_f32_16x16x32_bf16(af[i], be[j], acc_e[i][j], 0,0,0);
                    acc_t[i][j] = __builtin_amdgcn_mfma_f32_16x16x32_bf16(af[i], bt[j], acc_t[i][j], 0,0,0);
                  }
            }
            __syncthreads();
        }
    }

    float nse[4][4], nst[4][4];
    #pragma unroll
    for (int i=0;i<4;++i)
      #pragma unroll
      for (int rg=0;rg<4;++rg){ nse[i][rg]=0.f; nst[i][rg]=0.f; }
    #pragma unroll
    for (int j=0;j<4;++j){
        int hm = hb + wx*64 + j*16 + li;
        float dje = d_enc[b*H+hm], vje = enc_v[hm];
        float djt = d_tgt[b*H+hm], vjt = tgt_v[hm];
        #pragma unroll
        for (int i=0;i<4;++i)
          #pragma unroll
          for (int rg=0;rg<4;++rg){
            nse[i][rg] += vje * fast_tanh(acc_e[i][j][rg] + dje);
            nst[i][rg] += vjt * fast_tanh(acc_t[i][j][rg] + djt);
          }
    }
    #pragma unroll
    for (int off=1; off<16; off<<=1)
      #pragma unroll
      for (int i=0;i<4;++i)
        #pragma unroll
        for (int rg=0;rg<4;++rg){
          nse[i][rg] += __shfl_xor(nse[i][rg], off);
          nst[i][rg] += __shfl_xor(nst[i][rg], off);
        }
    if (li==0){
        #pragma unroll
        for (int i=0;i<4;++i)
          #pragma unroll
          for (int rg=0;rg<4;++rg){
            atomicAdd(&sc_e[b*N + n0 + wy*64 + i*16 + quad*4 + rg], nse[i][rg]);
            atomicAdd(&sc_t[b*N + n0 + wy*64 + i*16 + quad*4 + rg], nst[i][rg]);
          }
    }
}

// ---- fused softmax + context (grid B*8): in-block softmax from raw scores ----
__global__ __launch_bounds__(256) void k_ctx_sm(const unsigned short* __restrict__ Abf,
    const float* __restrict__ sc_e, const float* __restrict__ sc_t,
    float* __restrict__ ctx, float* __restrict__ ctxt)
{
    __shared__ float wse[512], wst[512];
    __shared__ float red[16];
    int b = blockIdx.x >> 3, c = blockIdx.x & 7, t = threadIdx.x;
    int lane = t & 63, wave = t >> 6;
    float e0 = sc_e[b*N+t], e1 = sc_e[b*N+256+t];
    float t0 = sc_t[b*N+t], t1 = sc_t[b*N+256+t];
    float me = fmaxf(e0,e1), mt = fmaxf(t0,t1);
    #pragma unroll
    for (int off=1; off<64; off<<=1){
        me = fmaxf(me, __shfl_xor(me, off));
        mt = fmaxf(mt, __shfl_xor(mt, off));
    }
    if (lane==0){ red[wave]=me; red[4+wave]=mt; }
    __syncthreads();
    me = fmaxf(fmaxf(red[0],red[1]), fmaxf(red[2],red[3]));
    mt = fmaxf(fmaxf(red[4],red[5]), fmaxf(red[6],red[7]));
    float ee0 = __expf(e0-me), ee1 = __expf(e1-me);
    float et0 = __expf(t0-mt), et1 = __expf(t1-mt);
    float se = ee0+ee1, st = et0+et1;
    #pragma unroll
    for (int off=1; off<64; off<<=1){
        se += __shfl_xor(se, off);
        st += __shfl_xor(st, off);
    }
    __syncthreads();
    if (lane==0){ red[8+wave]=se; red[12+wave]=st; }
    __syncthreads();
    float inve = 1.0f/(red[8]+red[9]+red[10]+red[11]);
    float invt = 1.0f/(red[12]+red[13]+red[14]+red[15]);
    wse[t]=ee0*inve; wse[256+t]=ee1*inve;
    wst[t]=et0*invt; wst[256+t]=et1*invt;
    __syncthreads();
    int n0 = c*64;
    float ae0=0.f, ae1=0.f, at0=0.f, at1=0.f;
    for (int n=0;n<64;++n){
        unsigned u = *(const unsigned*)&Abf[(size_t)(b*N+n0+n)*H + 2*t];
        float lo = __uint_as_float(u<<16);
        float hi = __uint_as_float(u & 0xFFFF0000u);
        float e = wse[n0+n], g = wst[n0+n];
        ae0 += e*lo; ae1 += e*hi; at0 += g*lo; at1 += g*hi;
    }
    atomicAdd(&ctx[b*H+2*t],   ae0); atomicAdd(&ctx[b*H+2*t+1],  ae1);
    atomicAdd(&ctxt[b*H+2*t],  at0); atomicAdd(&ctxt[b*H+2*t+1], at1);
}

// fallback: softmax+context from fp32 A
__global__ __launch_bounds__(256) void k_ctx_sm_f32(const float* __restrict__ A,
    const float* __restrict__ sc_e, const float* __restrict__ sc_t,
    float* __restrict__ ctx, float* __restrict__ ctxt)
{
    __shared__ float wse[512], wst[512];
    __shared__ float red[16];
    int b = blockIdx.x >> 2, c = blockIdx.x & 3, t = threadIdx.x;
    int lane = t & 63, wave = t >> 6;
    float e0 = sc_e[b*N+t], e1 = sc_e[b*N+256+t];
    float t0 = sc_t[b*N+t], t1 = sc_t[b*N+256+t];
    float me = fmaxf(e0,e1), mt = fmaxf(t0,t1);
    #pragma unroll
    for (int off=1; off<64; off<<=1){
        me = fmaxf(me, __shfl_xor(me, off));
        mt = fmaxf(mt, __shfl_xor(mt, off));
    }
    if (lane==0){ red[wave]=me; red[4+wave]=mt; }
    __syncthreads();
    me = fmaxf(fmaxf(red[0],red[1]), fmaxf(red[2],red[3]));
    mt = fmaxf(fmaxf(red[4],red[5]), fmaxf(red[6],red[7]));
    float ee0 = __expf(e0-me), ee1 = __expf(e1-me);
    float et0 = __expf(t0-mt), et1 = __expf(t1-mt);
    float se = ee0+ee1, st = et0+et1;
    #pragma unroll
    for (int off=1; off<64; off<<=1){
        se += __shfl_xor(se, off);
        st += __shfl_xor(st, off);
    }
    __syncthreads();
    if (lane==0){ red[8+wave]=se; red[12+wave]=st; }
    __syncthreads();
    float inve = 1.0f/(red[8]+red[9]+red[10]+red[11]);
    float invt = 1.0f/(red[12]+red[13]+red[14]+red[15]);
    wse[t]=ee0*inve; wse[256+t]=ee1*inve;
    wst[t]=et0*invt; wst[256+t]=et1*invt;
    __syncthreads();
    int n0 = c*128;
    float ae0=0.f, ae1=0.f, at0=0.f, at1=0.f;
    for (int n=0;n<128;++n){
        const float* ar = A + (size_t)(b*N + n0 + n)*H;
        float a0 = ar[t], a1 = ar[t+256];
        float e = wse[n0+n], g = wst[n0+n];
        ae0 += e*a0; ae1 += e*a1; at0 += g*a0; at1 += g*a1;
    }
    atomicAdd(&ctx[b*H+t],      ae0); atomicAdd(&ctx[b*H+t+256],  ae1);
    atomicAdd(&ctxt[b*H+t],     at0); atomicAdd(&ctxt[b*H+t+256], at1);
}

// ---- MFMA pointer scores (grid 2048): LDS staging, hoisted pointers ----
template<bool BF16A>
__global__ __launch_bounds__(256,2) void k_probs_mfma(
    const float* __restrict__ Af, const unsigned short* __restrict__ Abf,
    const unsigned short* __restrict__ Wp,
    const float* __restrict__ d_pe, const float* __restrict__ d_pt,
    const float* __restrict__ d_se,
    const float* __restrict__ ptr_v, float* __restrict__ probs)
{
    __shared__ __align__(16) unsigned short As[128*64];
    __shared__ __align__(16) unsigned short Bs[128*64];
    int blk = blockIdx.x;
    int b = blk >> 4; int nt = (blk >> 2) & 3; int ht = blk & 3;
    int n0 = nt*128, hb = ht*128;
    int t = threadIdx.x;
    int lane = t & 63, wave = t >> 6;
    int wy = wave >> 1, wx = wave & 1;
    int li = lane & 15, quad = lane >> 4;

    floatx4 acc[4][4];
    #pragma unroll
    for (int i=0;i<4;++i)
      #pragma unroll
      for (int j=0;j<4;++j) acc[i][j] = (floatx4)(0.0f);

    const unsigned short* rA[2]; const unsigned short* rB[2];
    #pragma unroll
    for (int ks=0;ks<2;++ks){
        int kb = (ks*4 + quad) ^ (li & 7);
        rA[ks] = &As[(wy*64 + li)*64 + kb*8];
        rB[ks] = &Bs[(wx*64 + li)*64 + kb*8];
    }

    if constexpr (BF16A){
        int rs = t >> 3;
        int kb = (t & 7) ^ (rs & 7);
        const unsigned short* gA[4]; const unsigned short* gB[4];
        unsigned short* lA[4]; unsigned short* lB[4];
        #pragma unroll
        for (int c=0;c<4;++c){
            int row = c*32 + rs;
            gA[c] = Abf + (size_t)(b*N + n0 + row)*H + kb*8;
            gB[c] = Wp  + (size_t)(hb + row)*H + kb*8;
            int s = c*256 + t;
            lA[c] = &As[(size_t)s*8]; lB[c] = &Bs[(size_t)s*8];
        }
        for (int kt=0; kt<8; ++kt){
            #pragma unroll
            for (int c=0;c<4;++c){
                gl16(gA[c], lA[c]); gA[c] += 64;
                gl16(gB[c], lB[c]); gB[c] += 64;
            }
            __syncthreads();
            #pragma unroll
            for (int ks=0;ks<2;++ks){
                short8 af[4], bg[4];
                #pragma unroll
                for (int i=0;i<4;++i) af[i] = *(const short8*)(rA[ks] + i*1024);
                #pragma unroll
                for (int j=0;j<4;++j) bg[j] = *(const short8*)(rB[ks] + j*1024);
                #pragma unroll
                for (int i=0;i<4;++i)
                  #pragma unroll
                  for (int j=0;j<4;++j)
                    acc[i][j] = __builtin_amdgcn_mfma_f32_16x16x32_bf16(af[i], bg[j], acc[i][j], 0,0,0);
            }
            __syncthreads();
        }
    } else {
        for (int kt=0; kt<8; ++kt){
            int k0 = kt*64;
            #pragma unroll
            for (int c=0;c<4;++c){
                int s = c*256 + t;
                int row = s >> 3;
                int kb = (s & 7) ^ (row & 7);
                const float* src = Af + (size_t)(b*N+n0+row)*H + k0 + kb*8;
                float4 lo = *(const float4*)src;
                float4 hi = *(const float4*)(src+4);
                uint4 p;
                p.x = pk2(lo.x,lo.y); p.y = pk2(lo.z,lo.w);
                p.z = pk2(hi.x,hi.y); p.w = pk2(hi.z,hi.w);
                *(uint4*)&As[(size_t)s*8] = p;
                gl16(&Wp[(size_t)(hb+row)*H + k0 + kb*8], &Bs[(size_t)s*8]);
            }
            __syncthreads();
            #pragma unroll
            for (int ks=0;ks<2;++ks){
                short8 af[4], bg[4];
                #pragma unroll
                for (int i=0;i<4;++i) af[i] = *(const short8*)(rA[ks] + i*1024);
                #pragma unroll
                for (int j=0;j<4;++j) bg[j] = *(const short8*)(rB[ks] + j*1024);
                #pragma unroll
                for (int i=0;i<4;++i)
                  #pragma unroll
                  for (int j=0;j<4;++j)
                    acc[i][j] = __builtin_amdgcn_mfma_f32_16x16x32_bf16(af[i], bg[j], acc[i][j], 0,0,0);
            }
            __syncthreads();
        }
    }

    float nsum[4][4];
    #pragma unroll
    for (int i=0;i<4;++i){ nsum[i][0]=0.f;nsum[i][1]=0.f;nsum[i][2]=0.f;nsum[i][3]=0.f; }
    #pragma unroll
    for (int j=0;j<4;++j){
        int hm = hb + wx*64 + j*16 + li;
        float se = d_se[b*H + hm];
        float de = d_pe[b*H + hm] + se;
        float dt = d_pt[b*H + hm] + se;
        float vj = ptr_v[hm];
        #pragma unroll
        for (int i=0;i<4;++i)
          #pragma unroll
          for (int rg=0;rg<4;++rg){
            float s = acc[i][j][rg];
            nsum[i][rg] += vj * (5.0f*fast_tanh(s + de) + fast_tanh(s + dt));
          }
    }
    #pragma unroll
    for (int off=1; off<16; off<<=1)
      #pragma unroll
      for (int i=0;i<4;++i)
        #pragma unroll
        for (int rg=0;rg<4;++rg)
          nsum[i][rg] += __shfl_xor(nsum[i][rg], off);
    if (li==0){
        #pragma unroll
        for (int i=0;i<4;++i)
          #pragma unroll
          for (int rg=0;rg<4;++rg)
            atomicAdd(&probs[b*N + n0 + wy*64 + i*16 + quad*4 + rg], nsum[i][rg]);
    }
}

extern "C" void kernel_launch(void* const* d_in, const int* in_sizes, int n_in,
                              void* d_out, int out_size, void* d_ws, size_t ws_size,
                              hipStream_t stream)
{
    (void)in_sizes; (void)n_in; (void)out_size;
    const float* A    = (const float*)d_in[0];
    const float* sem  = (const float*)d_in[1];
    const float* dec  = (const float*)d_in[2];
    const float* tgt  = (const float*)d_in[3];
    const float* lhh  = (const float*)d_in[4];
    const float* ptrv = (const float*)d_in[5];
    const float* ptrW = (const float*)d_in[6];
    const float* encv = (const float*)d_in[7];
    const float* encW = (const float*)d_in[8];
    const float* tgtv = (const float*)d_in[9];
    const float* tgtW = (const float*)d_in[10];
    const float* wih  = (const float*)d_in[11];
    const float* whh  = (const float*)d_in[12];
    const float* bih  = (const float*)d_in[13];
    const float* bhh  = (const float*)d_in[14];

    float* probs_out = (float*)d_out;
    float* hh_out    = (float*)d_out + B*N;

    float* ws = (float*)d_ws;
    const size_t S = (size_t)B*H;          // 65536
    float* d_enc = ws;
    float* d_tgt = ws + S;
    float* d_se  = ws + 2*S;
    float* sc_e  = ws + 3*S;
    float* sc_t  = ws + 4*S;
    float* ctx   = ws + 5*S;
    float* ctxt  = ws + 6*S;
    float* d_pe  = ws + 7*S;
    float* d_pt  = ws + 8*S;
    float* gx    = ws + 9*S;               // 3S
    float* gh    = ws + 12*S;              // 3S
    unsigned short* bfb  = (unsigned short*)(ws + 15*S);
    const size_t WH = (size_t)H*H;
    const size_t WG = (size_t)3*H*H;
    unsigned short* We_s  = bfb;
    unsigned short* Wt_s  = We_s + WH;
    unsigned short* Wp_s  = Wt_s + WH;
    unsigned short* We_d  = Wp_s + WH;
    unsigned short* Wt_d  = We_d + WH;
    unsigned short* Wp_c  = Wt_d + WH;
    unsigned short* Wp_e  = Wp_c + WH;
    unsigned short* Wih_b = Wp_e + WH;
    unsigned short* Whh_b = Wih_b + WG;
    unsigned short* Xbf   = Whh_b + WG;
    unsigned short* Hbf   = Xbf + S;
    unsigned short* Tbf   = Hbf + S;
    unsigned short* Sbf   = Tbf + S;
    unsigned short* HNbf  = Sbf + S;
    unsigned short* Abf   = HNbf + S;

    const size_t need_full = 15*S*sizeof(float)
        + (7*WH + 2*WG + 5*S + (size_t)B*N*H) * sizeof(unsigned short);
    const bool big = ws_size >= need_full;

    hipMemsetAsync(sc_e, 0, 4*S*sizeof(float), stream);   // sc_e, sc_t, ctx, ctxt
    hipMemsetAsync(probs_out, 0, (size_t)B*N*sizeof(float), stream);

    int castA_blocks = big ? (int)(((size_t)B*N*H)/(256*8)) : 0;
    k_cast_all<<<6784 + castA_blocks, 256, 0, stream>>>(encW, tgtW, ptrW, wih, whh,
        dec, lhh, tgt, sem, A,
        We_s, Wt_s, Wp_s, We_d, Wt_d, Wp_c, Wp_e, Wih_b, Whh_b,
        Xbf, Hbf, Tbf, Sbf, Abf);

    k_pre<<<32, 256, 0, stream>>>(Xbf, Hbf, Tbf, Sbf, Wih_b, Whh_b, Wt_d, Wp_e,
        gx, gh, d_tgt, d_se);
    k_gru_gate<<<256, 256, 0, stream>>>(gx, gh, lhh, bih, bhh, hh_out, HNbf);
    k_bias0<<<4, 256, 0, stream>>>(HNbf, We_d, d_enc);

    if (big)
        k_scores_fused<true ><<<2048, 256, 0, stream>>>(A, Abf, We_s, Wt_s, d_enc, d_tgt, encv, tgtv, sc_e, sc_t);
    else
        k_scores_fused<false><<<2048, 256, 0, stream>>>(A, Abf, We_s, Wt_s, d_enc, d_tgt, encv, tgtv, sc_e, sc_t);

    if (big)
        k_ctx_sm<<<B*8, 256, 0, stream>>>(Abf, sc_e, sc_t, ctx, ctxt);
    else
        k_ctx_sm_f32<<<B*4, 256, 0, stream>>>(A, sc_e, sc_t, ctx, ctxt);

    k_dptr_gemm<<<8, 256, 0, stream>>>(ctx, ctxt, Wp_c, d_pe, d_pt);

    if (big)
        k_probs_mfma<true ><<<2048, 256, 0, stream>>>(A, Abf, Wp_s, d_pe, d_pt, d_se, ptrv, probs_out);
    else
        k_probs_mfma<false><<<2048, 256, 0, stream>>>(A, Abf, Wp_s, d_pe, d_pt, d_se, ptrv, probs_out);
}